// Round 11
// baseline (80.894 us; speedup 1.0000x reference)
//
#include <hip/hip_runtime.h>
#include <math.h>
#include <stdint.h>

#define BATCH    2048
#define NCHOICES 2048
#define NV       8
#define VS       256
#define KTOT     2048

typedef unsigned short u16;
typedef __attribute__((ext_vector_type(8))) short    bf16x8;
typedef __attribute__((ext_vector_type(8))) u16      u16x8;
typedef __attribute__((ext_vector_type(4))) float    f32x4;

__device__ __forceinline__ u16 f2bf_rne(float x) {
    unsigned u = __float_as_uint(x);
    return (u16)((u + 0x7FFFu + ((u >> 16) & 1u)) >> 16);
}

// ---------------------------------------------------------------------------
// Kernel 1: NORMALIZED bf16 hi/lo split planes + sigmoid(nand_weight).
// (R8/R9, verified: absmax 1.45e-11)
// ---------------------------------------------------------------------------
__global__ __launch_bounds__(256) void prep_convert(
    const float* __restrict__ Q, const float* __restrict__ W,
    const float* __restrict__ NWT,
    u16* __restrict__ Qh, u16* __restrict__ Ql,
    u16* __restrict__ Wh, u16* __restrict__ Wl,
    float* __restrict__ snw)
{
    const int row = blockIdx.x;
    const int t   = threadIdx.x;
    const int n   = t >> 5;
    const int l   = t & 31;

    const float* src; u16 *dh, *dl;
    if (row < BATCH) {
        src = Q + (size_t)row * KTOT;
        dh = Qh + (size_t)row * KTOT; dl = Ql + (size_t)row * KTOT;
    } else {
        src = W + (size_t)(row - BATCH) * KTOT;
        dh = Wh + (size_t)(row - BATCH) * KTOT; dl = Wl + (size_t)(row - BATCH) * KTOT;
    }

    const int idx = n * VS + l * 8;
    float4 x0 = *(const float4*)(src + idx);
    float4 x1 = *(const float4*)(src + idx + 4);
    float xs[8] = {x0.x, x0.y, x0.z, x0.w, x1.x, x1.y, x1.z, x1.w};

    float s = 0.0f;
    #pragma unroll
    for (int j = 0; j < 8; ++j) s = fmaf(xs[j], xs[j], s);
    #pragma unroll
    for (int m = 1; m < 32; m <<= 1) s += __shfl_xor(s, m, 64);
    const float rn = 1.0f / fmaxf(sqrtf(s), 1e-6f);

    u16x8 hv, lv;
    #pragma unroll
    for (int j = 0; j < 8; ++j) {
        float xn = xs[j] * rn;
        u16 h = f2bf_rne(xn);
        float hf = __uint_as_float(((unsigned)h) << 16);
        hv[j] = h;
        lv[j] = f2bf_rne(xn - hf);
    }
    *(u16x8*)(dh + idx) = hv;
    *(u16x8*)(dl + idx) = lv;

    if (row >= BATCH && t < NV) {
        const int c = row - BATCH;
        float x = NWT[(size_t)c * NV + t];
        snw[(size_t)c * NV + t] = 1.0f / (1.0f + expf(-x));
    }
}

// ---------------------------------------------------------------------------
// Kernel 2: MFMA GEMM v11 — cross-tile operand prefetch.
// BM=128, BN=256, BK=32, 8 waves (64x64), 3 LDS bufs (144 KiB, 1 block/CU),
// grid 8x16x2 XCD-swizzled, split-K x2, pass-major MFMAs (R9).
// Per tile: passes use ah loaded LAST tile; bh/al/bl read at tile start
// overlap pass1 via lgkm staircase; ah(t+1) read mid-tile after a
// vmcnt(0)+barrier (exact: only stage(t+1)+snw outstanding there);
// STAGE(t+2) issued between pass2/pass3. LDS service hides under MFMAs.
// ---------------------------------------------------------------------------
__device__ __forceinline__ void gload16(const void* g, void* l) {
    __builtin_amdgcn_global_load_lds(
        (__attribute__((address_space(1))) void*)(uintptr_t)g,
        (__attribute__((address_space(3))) void*)(uint32_t)(uintptr_t)l,
        16, 0, 0);
}

#define RD16(dst, va, OFF) \
    asm volatile("ds_read_b128 %0, %1 offset:" OFF : "=v"(dst) : "v"(va))

#define GLD_F32(dst, p) \
    asm volatile("global_load_dword %0, %1, off" : "=v"(dst) : "v"(p))

__device__ __forceinline__ void chunk_epi(f32x4 (&acc)[4][4], f32x4 (&prod)[4][4],
                                          float sn0, float sn1, float sn2, float sn3)
{
    float vvv[4] = {2.f*sn0-1.f, 2.f*sn1-1.f, 2.f*sn2-1.f, 2.f*sn3-1.f};
    float uuu[4] = {1.f-sn0, 1.f-sn1, 1.f-sn2, 1.f-sn3};
    #pragma unroll
    for (int m = 0; m < 4; ++m)
        #pragma unroll
        for (int i = 0; i < 4; ++i)
            #pragma unroll
            for (int n = 0; n < 4; ++n) {
                float cosv = acc[m][n][i];
                float Lk = fmaxf(cosv, 0.01f * cosv);
                prod[m][n][i] *= fmaf(Lk, vvv[n], uuu[n]);
                acc[m][n][i] = 0.f;
            }
}

__global__ __launch_bounds__(512, 2) void nand_mfma11(
    const u16* __restrict__ Qh, const u16* __restrict__ Ql,
    const u16* __restrict__ Wh, const u16* __restrict__ Wl,
    const float* __restrict__ snw, float* __restrict__ part)
{
    // 3 bufs x [Ah(128x32)=4096 u16 | Al=4096 | Bh(256x32)=8192 | Bl=8192]
    __shared__ __align__(16) u16 L[3][24576];   // 144 KiB

    const int tid  = threadIdx.x;
    const int lane = tid & 63;
    const int wave = tid >> 6;                  // 0..7

    // XCD-aware block swizzle (256 blocks, 256%8==0 -> bijective)
    const int f    = blockIdx.x + 8 * blockIdx.y + 128 * blockIdx.z;
    const int virt = (f & 7) * 32 + (f >> 3);
    const int bx   = virt & 7;
    const int by   = (virt >> 3) & 15;
    const int z    = virt >> 7;

    const int wr  = (wave >> 2) * 64;
    const int wc  = (wave & 3) * 64;
    const int bm0 = by * 128;
    const int bn0 = bx * 256;
    const int kb  = z * 1024;

    const int fr = lane & 15;
    const int gi = lane >> 4;

    // ---- staging geometry: 6 x 16B granules / thread / K-tile ----
    const int gr = tid >> 2;
    const int sw = 8 * ((tid & 3) ^ ((gr >> 1) & 3));

    const u16* sAh  = Qh + (size_t)(bm0 + gr) * KTOT + kb + sw;
    const u16* sAl  = Ql + (size_t)(bm0 + gr) * KTOT + kb + sw;
    const u16* sBh0 = Wh + (size_t)(bn0 + gr) * KTOT + kb + sw;
    const u16* sBh1 = Wh + (size_t)(bn0 + 128 + gr) * KTOT + kb + sw;
    const u16* sBl0 = Wl + (size_t)(bn0 + gr) * KTOT + kb + sw;
    const u16* sBl1 = Wl + (size_t)(bn0 + 128 + gr) * KTOT + kb + sw;

    uint32_t rOffB = 0;          // read buf byte offset   (t % 3)   * 49152
    uint32_t nOffB = 49152;      // next buf byte offset   (t+1 % 3) * 49152
    uint32_t sOffU = 0;          // stage buf u16 offset   (t+2 % 3) * 24576
    int      ktn   = 0;          // tile index being staged

    #define STAGE_T() do { u16* Lb_ = ((u16*)L) + sOffU; const int ko = ktn * 32; \
        gload16(sAh  + ko, Lb_ + tid * 8);                                   \
        gload16(sAl  + ko, Lb_ + 4096  + tid * 8);                           \
        gload16(sBh0 + ko, Lb_ + 8192  + tid * 8);                           \
        gload16(sBh1 + ko, Lb_ + 12288 + tid * 8);                           \
        gload16(sBl0 + ko, Lb_ + 16384 + tid * 8);                           \
        gload16(sBl1 + ko, Lb_ + 20480 + tid * 8);                           \
    } while (0)

    const uint32_t ldsBase = (uint32_t)(uintptr_t)&L[0][0];
    const uint32_t swz16   = (uint32_t)((gi ^ ((fr >> 1) & 3)) * 16);
    const uint32_t vbaseA  = ldsBase + (uint32_t)((wr + fr) * 64) + swz16;
    const uint32_t vbaseB  = ldsBase + 16384u + (uint32_t)((wc + fr) * 64) + swz16;

    #define MF(AR, BR, M, N) \
        acc[M][N] = __builtin_amdgcn_mfma_f32_16x16x32_bf16(AR[M], BR[N], acc[M][N], 0, 0, 0)
    #define PASS(AR, BR) do {                                                \
        MF(AR, BR, 0, 0); MF(AR, BR, 0, 1); MF(AR, BR, 0, 2); MF(AR, BR, 0, 3); \
        MF(AR, BR, 1, 0); MF(AR, BR, 1, 1); MF(AR, BR, 1, 2); MF(AR, BR, 1, 3); \
        MF(AR, BR, 2, 0); MF(AR, BR, 2, 1); MF(AR, BR, 2, 2); MF(AR, BR, 2, 3); \
        MF(AR, BR, 3, 0); MF(AR, BR, 3, 1); MF(AR, BR, 3, 2); MF(AR, BR, 3, 3); \
    } while (0)

    // CURA: A-operand set for this tile (loaded last tile);
    // NXTA: set to preload with tile t+1's ah during this tile.
    #define TILE(CURA, NXTA, DOREAD, DOSTAGE, DOSNW, LG2, LG3, DOBAR) do {   \
        if (DOSNW) { GLD_F32(sn0, snwP);       GLD_F32(sn1, snwP + 128);     \
                     GLD_F32(sn2, snwP + 256); GLD_F32(sn3, snwP + 384);     \
                     __builtin_amdgcn_sched_barrier(0); }                    \
        {                                                                    \
        const uint32_t vaA = vbaseA + rOffB;                                 \
        const uint32_t vaB = vbaseB + rOffB;                                 \
        RD16(bh[0], vaB, "0");     RD16(bh[1], vaB, "1024");                 \
        RD16(bh[2], vaB, "2048");  RD16(bh[3], vaB, "3072");                 \
        RD16(al[0], vaA, "8192");  RD16(al[1], vaA, "9216");                 \
        RD16(al[2], vaA, "10240"); RD16(al[3], vaA, "11264");                \
        RD16(bl[0], vaB, "16384"); RD16(bl[1], vaB, "17408");                \
        RD16(bl[2], vaB, "18432"); RD16(bl[3], vaB, "19456");                \
        }                                                                    \
        __builtin_amdgcn_s_setprio(1);                                       \
        asm volatile("s_waitcnt lgkmcnt(8)");                                \
        __builtin_amdgcn_sched_barrier(0);                                   \
        PASS(CURA, bh);                                                      \
        __builtin_amdgcn_s_setprio(0);                                       \
        asm volatile("s_waitcnt vmcnt(0)");                                  \
        __builtin_amdgcn_s_barrier();                                        \
        if (DOREAD) {                                                        \
            const uint32_t vaAn = vbaseA + nOffB;                            \
            RD16(NXTA[0], vaAn, "0");    RD16(NXTA[1], vaAn, "1024");        \
            RD16(NXTA[2], vaAn, "2048"); RD16(NXTA[3], vaAn, "3072");        \
        }                                                                    \
        __builtin_amdgcn_s_setprio(1);                                       \
        asm volatile("s_waitcnt lgkmcnt(" LG2 ")");                          \
        __builtin_amdgcn_sched_barrier(0);                                   \
        PASS(al, bh);                                                        \
        __builtin_amdgcn_s_setprio(0);                                       \
        if (DOSTAGE) STAGE_T();                                              \
        __builtin_amdgcn_s_setprio(1);                                       \
        asm volatile("s_waitcnt lgkmcnt(" LG3 ")");                          \
        __builtin_amdgcn_sched_barrier(0);                                   \
        PASS(CURA, bl);                                                      \
        __builtin_amdgcn_s_setprio(0);                                       \
        if (DOBAR) __builtin_amdgcn_s_barrier();                             \
        rOffB = nOffB;                                                       \
        nOffB += 49152u; if (nOffB == 147456u) nOffB = 0;                    \
        sOffU += 24576u; if (sOffU == 73728u)  sOffU = 0;                    \
        ++ktn;                                                               \
    } while (0)

    bf16x8 ahA[4], ahB[4], bh[4], al[4], bl[4];
    f32x4 acc[4][4], prod[4][4];
    float sn0, sn1, sn2, sn3;
    #pragma unroll
    for (int m = 0; m < 4; ++m)
        #pragma unroll
        for (int n = 0; n < 4; ++n) {
            acc[m][n]  = (f32x4){0.f, 0.f, 0.f, 0.f};
            prod[m][n] = (f32x4){1.f, 1.f, 1.f, 1.f};
        }

    const float* snwBase = snw + (size_t)(bn0 + wc + fr) * NV + z * 4;

    // prologue: stage tiles 0,1; wait tile 0; preload ahA(0)
    STAGE_T();                                  // sOffU=0, ktn=0
    sOffU = 24576; ktn = 1;
    STAGE_T();                                  // buf1, tile1
    sOffU = 49152; ktn = 2;
    asm volatile("s_waitcnt vmcnt(6)");
    __builtin_amdgcn_s_barrier();
    {
        const uint32_t vaA = vbaseA;            // rOffB = 0
        RD16(ahA[0], vaA, "0");    RD16(ahA[1], vaA, "1024");
        RD16(ahA[2], vaA, "2048"); RD16(ahA[3], vaA, "3072");
    }

    #pragma unroll 1
    for (int cc = 0; cc < 3; ++cc) {
        const float* snwP = snwBase + cc;
        TILE(ahA, ahB, 1, 1, 0, "8", "4", 1);
        TILE(ahB, ahA, 1, 1, 0, "8", "4", 1);
        TILE(ahA, ahB, 1, 1, 0, "8", "4", 1);
        TILE(ahB, ahA, 1, 1, 0, "8", "4", 1);
        TILE(ahA, ahB, 1, 1, 0, "8", "4", 1);
        TILE(ahB, ahA, 1, 1, 0, "8", "4", 1);
        TILE(ahA, ahB, 1, 1, 0, "8", "4", 1);
        TILE(ahB, ahA, 1, 1, 1, "8", "4", 1);   // snw for chunk cc
        chunk_epi(acc, prod, sn0, sn1, sn2, sn3);
    }
    {   // last chunk: tiles 24..31 (stage ends at t=29 -> tile 31)
        const float* snwP = snwBase + 3;
        TILE(ahA, ahB, 1, 1, 0, "8", "4", 1);   // t=24
        TILE(ahB, ahA, 1, 1, 0, "8", "4", 1);   // t=25
        TILE(ahA, ahB, 1, 1, 0, "8", "4", 1);   // t=26
        TILE(ahB, ahA, 1, 1, 0, "8", "4", 1);   // t=27
        TILE(ahA, ahB, 1, 1, 0, "8", "4", 1);   // t=28
        TILE(ahB, ahA, 1, 1, 0, "8", "4", 1);   // t=29 (stages tile 31)
        TILE(ahA, ahB, 1, 0, 0, "8", "4", 1);   // t=30: no stage
        TILE(ahB, ahA, 0, 0, 1, "4", "0", 0);   // t=31: no read, snw
        chunk_epi(acc, prod, sn0, sn1, sn2, sn3);
    }

    const int ri = gi * 4;
    float* P = part + (size_t)z * BATCH * NCHOICES;
    #pragma unroll
    for (int m = 0; m < 4; ++m)
        #pragma unroll
        for (int i = 0; i < 4; ++i) {
            const int row = bm0 + wr + m * 16 + ri + i;
            float* pr = P + (size_t)row * NCHOICES + bn0 + wc + fr;
            #pragma unroll
            for (int n = 0; n < 4; ++n) pr[n * 16] = prod[m][n][i];
        }

    #undef STAGE_T
    #undef MF
    #undef PASS
    #undef TILE
}

// ---------------------------------------------------------------------------
// Kernel 3: combine 2 split-K partial products.
// ---------------------------------------------------------------------------
__global__ __launch_bounds__(256) void combine_kernel(
    const float* __restrict__ p, float* __restrict__ out)
{
    const size_t NN = (size_t)BATCH * NCHOICES;
    size_t i = ((size_t)blockIdx.x * 256 + threadIdx.x) * 4;
    float4 a = *(const float4*)(p + i);
    float4 b = *(const float4*)(p + NN + i);
    float4 o;
    o.x = a.x * b.x;
    o.y = a.y * b.y;
    o.z = a.z * b.z;
    o.w = a.w * b.w;
    *(float4*)(out + i) = o;
}

// ---------------------------------------------------------------------------
// Fallback: R1's verified fp32 vector-FMA path (used if ws too small).
// ---------------------------------------------------------------------------
__global__ __launch_bounds__(256) void prep_kernel(
    const float* __restrict__ Q, const float* __restrict__ W,
    const float* __restrict__ NWT,
    float* __restrict__ rq, float* __restrict__ rw, float* __restrict__ snw)
{
    const int row = blockIdx.x;
    const int t   = threadIdx.x;
    const int n   = t >> 5;
    const int l   = t & 31;

    const float* src; float* dst;
    if (row < BATCH) { src = Q + (size_t)row * KTOT; dst = rq + (size_t)row * NV; }
    else { src = W + (size_t)(row - BATCH) * KTOT; dst = rw + (size_t)(row - BATCH) * NV; }

    const float* v = src + n * VS + l * 8;
    float4 a = *(const float4*)(v);
    float4 b = *(const float4*)(v + 4);
    float s = a.x*a.x + a.y*a.y + a.z*a.z + a.w*a.w
            + b.x*b.x + b.y*b.y + b.z*b.z + b.w*b.w;
    #pragma unroll
    for (int m = 1; m < 32; m <<= 1) s += __shfl_xor(s, m, 64);
    if (l == 0) dst[n] = 1.0f / fmaxf(sqrtf(s), 1e-6f);
    if (row >= BATCH && t < NV) {
        const int c = row - BATCH;
        float x = NWT[(size_t)c * NV + t];
        snw[(size_t)c * NV + t] = 1.0f / (1.0f + expf(-x));
    }
}

__global__ __launch_bounds__(256, 2) void nand_gemm(
    const float* __restrict__ Q, const float* __restrict__ W,
    const float* __restrict__ rq, const float* __restrict__ rw,
    const float* __restrict__ snw, float* __restrict__ out)
{
    __shared__ __align__(16) float As[16][128 + 4];
    __shared__ __align__(16) float Bs[16][128 + 4];
    __shared__ __align__(16) float rqs[128];
    __shared__ __align__(16) float rws[128];
    __shared__ __align__(16) float sns[128];

    const int tid = threadIdx.x;
    const int tx  = tid & 15;
    const int ty  = tid >> 4;
    const int bm0 = blockIdx.y * 128;
    const int bn0 = blockIdx.x * 128;
    const int lr  = tid >> 2;
    const int lk  = (tid & 3) * 4;

    float prod[8][8];
    #pragma unroll
    for (int i = 0; i < 8; ++i)
        #pragma unroll
        for (int j = 0; j < 8; ++j) prod[i][j] = 1.0f;

    for (int n = 0; n < NV; ++n) {
        float acc[8][8];
        #pragma unroll
        for (int i = 0; i < 8; ++i)
            #pragma unroll
            for (int j = 0; j < 8; ++j) acc[i][j] = 0.0f;

        #pragma unroll 1
        for (int kt = 0; kt < VS / 16; ++kt) {
            const int k0 = n * VS + kt * 16;
            __syncthreads();
            {
                const float* qrow = Q + (size_t)(bm0 + lr) * KTOT + k0 + lk;
                float4 a0 = *(const float4*)(qrow);
                float4 a1 = *(const float4*)(qrow + (size_t)64 * KTOT);
                As[lk + 0][lr] = a0.x; As[lk + 1][lr] = a0.y;
                As[lk + 2][lr] = a0.z; As[lk + 3][lr] = a0.w;
                As[lk + 0][64 + lr] = a1.x; As[lk + 1][64 + lr] = a1.y;
                As[lk + 2][64 + lr] = a1.z; As[lk + 3][64 + lr] = a1.w;

                const float* wrow = W + (size_t)(bn0 + lr) * KTOT + k0 + lk;
                float4 b0 = *(const float4*)(wrow);
                float4 b1 = *(const float4*)(wrow + (size_t)64 * KTOT);
                Bs[lk + 0][lr] = b0.x; Bs[lk + 1][lr] = b0.y;
                Bs[lk + 2][lr] = b0.z; Bs[lk + 3][lr] = b0.w;
                Bs[lk + 0][64 + lr] = b1.x; Bs[lk + 1][64 + lr] = b1.y;
                Bs[lk + 2][64 + lr] = b1.z; Bs[lk + 3][64 + lr] = b1.w;
            }
            if (kt == 0) {
                for (int i = tid; i < 3 * 128; i += 256) {
                    if (i < 128)      rqs[i]       = rq[(size_t)(bm0 + i) * NV + n];
                    else if (i < 256) rws[i - 128] = rw[(size_t)(bn0 + i - 128) * NV + n];
                    else              sns[i - 256] = snw[(size_t)(bn0 + i - 256) * NV + n];
                }
            }
            __syncthreads();

            #pragma unroll
            for (int kk = 0; kk < 16; ++kk) {
                float4 a0 = *(const float4*)&As[kk][ty * 4];
                float4 a1 = *(const float4*)&As[kk][64 + ty * 4];
                float4 b0 = *(const float4*)&Bs[kk][tx * 4];
                float4 b1 = *(const float4*)&Bs[kk][64 + tx * 4];
                float ar[8] = {a0.x, a0.y, a0.z, a0.w, a1.x, a1.y, a1.z, a1.w};
                float br[8] = {b0.x, b0.y, b0.z, b0.w, b1.x, b1.y, b1.z, b1.w};
                #pragma unroll
                for (int i = 0; i < 8; ++i)
                    #pragma unroll
                    for (int j = 0; j < 8; ++j)
                        acc[i][j] = fmaf(ar[i], br[j], acc[i][j]);
            }
        }

        float rwv[8], uu[8], vv[8];
        #pragma unroll
        for (int j = 0; j < 8; ++j) {
            int cc = (j < 4) ? (tx * 4 + j) : (64 + tx * 4 + (j - 4));
            rwv[j] = rws[cc];
            float s = sns[cc];
            uu[j] = 1.0f - s;
            vv[j] = 2.0f * s - 1.0f;
        }
        #pragma unroll
        for (int i = 0; i < 8; ++i) {
            int r = (i < 4) ? (ty * 4 + i) : (64 + ty * 4 + (i - 4));
            float rqv = rqs[r];
            #pragma unroll
            for (int j = 0; j < 8; ++j) {
                float cosv = acc[i][j] * rqv * rwv[j];
                float Lk = fmaxf(cosv, 0.01f * cosv);
                prod[i][j] *= fmaf(Lk, vv[j], uu[j]);
            }
        }
    }

    #pragma unroll
    for (int i = 0; i < 8; ++i) {
        int r = (i < 4) ? (ty * 4 + i) : (64 + ty * 4 + (i - 4));
        float* orow = out + (size_t)(bm0 + r) * NCHOICES + bn0;
        float4 o0 = {prod[i][0], prod[i][1], prod[i][2], prod[i][3]};
        float4 o1 = {prod[i][4], prod[i][5], prod[i][6], prod[i][7]};
        *(float4*)(orow + tx * 4)      = o0;
        *(float4*)(orow + 64 + tx * 4) = o1;
    }
}

extern "C" void kernel_launch(void* const* d_in, const int* in_sizes, int n_in,
                              void* d_out, int out_size, void* d_ws, size_t ws_size,
                              hipStream_t stream)
{
    const float* Q   = (const float*)d_in[0];
    const float* W   = (const float*)d_in[1];
    const float* NWT = (const float*)d_in[2];
    float* out = (float*)d_out;

    char* w = (char*)d_ws;
    float* rq  = (float*)w; w += (size_t)BATCH    * NV * 4;
    float* rwn = (float*)w; w += (size_t)NCHOICES * NV * 4;
    float* snw = (float*)w; w += (size_t)NCHOICES * NV * 4;
    u16* Qh = (u16*)w; w += (size_t)BATCH * KTOT * 2;
    u16* Ql = (u16*)w; w += (size_t)BATCH * KTOT * 2;
    u16* Wh = (u16*)w; w += (size_t)NCHOICES * KTOT * 2;
    u16* Wl = (u16*)w; w += (size_t)NCHOICES * KTOT * 2;
    float* part = (float*)w; w += (size_t)2 * BATCH * NCHOICES * 4;
    const size_t needed = (size_t)(w - (char*)d_ws);

    if (ws_size >= needed) {
        prep_convert<<<BATCH + NCHOICES, 256, 0, stream>>>(
            Q, W, NWT, Qh, Ql, Wh, Wl, snw);
        dim3 grid(NCHOICES / 256, BATCH / 128, 2);
        nand_mfma11<<<grid, 512, 0, stream>>>(Qh, Ql, Wh, Wl, snw, part);
        combine_kernel<<<(BATCH * NCHOICES / 4) / 256, 256, 0, stream>>>(part, out);
    } else {
        prep_kernel<<<BATCH + NCHOICES, 256, 0, stream>>>(Q, W, NWT, rq, rwn, snw);
        dim3 grid(NCHOICES / 128, BATCH / 128);
        nand_gemm<<<grid, 256, 0, stream>>>(Q, W, rq, rwn, snw, out);
    }
}

// Round 12
// 75.585 us; speedup vs baseline: 1.0702x; 1.0702x over previous
//
#include <hip/hip_runtime.h>
#include <math.h>
#include <stdint.h>

#define BATCH    2048
#define NCHOICES 2048
#define NV       8
#define VS       256
#define KTOT     2048

typedef unsigned short u16;
typedef __attribute__((ext_vector_type(8))) short    bf16x8;
typedef __attribute__((ext_vector_type(8))) u16      u16x8;
typedef __attribute__((ext_vector_type(4))) float    f32x4;

__device__ __forceinline__ u16 f2bf_rne(float x) {
    unsigned u = __float_as_uint(x);
    return (u16)((u + 0x7FFFu + ((u >> 16) & 1u)) >> 16);
}

// ---------------------------------------------------------------------------
// Kernel 1: NORMALIZED bf16 hi/lo split planes + sigmoid(nand_weight).
// (R8/R9, verified: absmax 1.45e-11)
// ---------------------------------------------------------------------------
__global__ __launch_bounds__(256) void prep_convert(
    const float* __restrict__ Q, const float* __restrict__ W,
    const float* __restrict__ NWT,
    u16* __restrict__ Qh, u16* __restrict__ Ql,
    u16* __restrict__ Wh, u16* __restrict__ Wl,
    float* __restrict__ snw)
{
    const int row = blockIdx.x;
    const int t   = threadIdx.x;
    const int n   = t >> 5;
    const int l   = t & 31;

    const float* src; u16 *dh, *dl;
    if (row < BATCH) {
        src = Q + (size_t)row * KTOT;
        dh = Qh + (size_t)row * KTOT; dl = Ql + (size_t)row * KTOT;
    } else {
        src = W + (size_t)(row - BATCH) * KTOT;
        dh = Wh + (size_t)(row - BATCH) * KTOT; dl = Wl + (size_t)(row - BATCH) * KTOT;
    }

    const int idx = n * VS + l * 8;
    float4 x0 = *(const float4*)(src + idx);
    float4 x1 = *(const float4*)(src + idx + 4);
    float xs[8] = {x0.x, x0.y, x0.z, x0.w, x1.x, x1.y, x1.z, x1.w};

    float s = 0.0f;
    #pragma unroll
    for (int j = 0; j < 8; ++j) s = fmaf(xs[j], xs[j], s);
    #pragma unroll
    for (int m = 1; m < 32; m <<= 1) s += __shfl_xor(s, m, 64);
    const float rn = 1.0f / fmaxf(sqrtf(s), 1e-6f);

    u16x8 hv, lv;
    #pragma unroll
    for (int j = 0; j < 8; ++j) {
        float xn = xs[j] * rn;
        u16 h = f2bf_rne(xn);
        float hf = __uint_as_float(((unsigned)h) << 16);
        hv[j] = h;
        lv[j] = f2bf_rne(xn - hf);
    }
    *(u16x8*)(dh + idx) = hv;
    *(u16x8*)(dl + idx) = lv;

    if (row >= BATCH && t < NV) {
        const int c = row - BATCH;
        float x = NWT[(size_t)c * NV + t];
        snw[(size_t)c * NV + t] = 1.0f / (1.0f + expf(-x));
    }
}

// ---------------------------------------------------------------------------
// Kernel 2: MFMA GEMM v12 — m201-style 3-phase schedule on R10 geometry.
// BM=128, BN=256, BK=32, 8 waves (64x64), 3 LDS bufs (144 KiB, 1 block/CU),
// grid 8x16x2 XCD-swizzled, split-K x2, pass-major MFMAs.
// Per K-tile, 3 phases (one per split pass): {stage pair | lgkm0 | 16 MFMA |
// issue NEXT phase's reads | barrier}. Reads always issued one phase early
// (pre-barrier) so LDS service overlaps other waves' MFMA window; stage DMAs
// spread 2-per-phase; vmcnt(6) once per tile (never 0 in the loop).
// ---------------------------------------------------------------------------
__device__ __forceinline__ void gload16(const void* g, void* l) {
    __builtin_amdgcn_global_load_lds(
        (__attribute__((address_space(1))) void*)(uintptr_t)g,
        (__attribute__((address_space(3))) void*)(uint32_t)(uintptr_t)l,
        16, 0, 0);
}

#define RD16(dst, va, OFF) \
    asm volatile("ds_read_b128 %0, %1 offset:" OFF : "=v"(dst) : "v"(va))

#define GLD_F32(dst, p) \
    asm volatile("global_load_dword %0, %1, off" : "=v"(dst) : "v"(p))

__device__ __forceinline__ void chunk_epi(f32x4 (&acc)[4][4], f32x4 (&prod)[4][4],
                                          float sn0, float sn1, float sn2, float sn3)
{
    float vvv[4] = {2.f*sn0-1.f, 2.f*sn1-1.f, 2.f*sn2-1.f, 2.f*sn3-1.f};
    float uuu[4] = {1.f-sn0, 1.f-sn1, 1.f-sn2, 1.f-sn3};
    #pragma unroll
    for (int m = 0; m < 4; ++m)
        #pragma unroll
        for (int i = 0; i < 4; ++i)
            #pragma unroll
            for (int n = 0; n < 4; ++n) {
                float cosv = acc[m][n][i];
                float Lk = fmaxf(cosv, 0.01f * cosv);
                prod[m][n][i] *= fmaf(Lk, vvv[n], uuu[n]);
                acc[m][n][i] = 0.f;
            }
}

__global__ __launch_bounds__(512, 2) void nand_mfma12(
    const u16* __restrict__ Qh, const u16* __restrict__ Ql,
    const u16* __restrict__ Wh, const u16* __restrict__ Wl,
    const float* __restrict__ snw, float* __restrict__ part)
{
    // 3 bufs x [Ah(128x32)=4096 u16 | Al=4096 | Bh(256x32)=8192 | Bl=8192]
    __shared__ __align__(16) u16 L[3][24576];   // 144 KiB

    const int tid  = threadIdx.x;
    const int lane = tid & 63;
    const int wave = tid >> 6;                  // 0..7

    // XCD-aware block swizzle (256 blocks, 256%8==0 -> bijective)
    const int f    = blockIdx.x + 8 * blockIdx.y + 128 * blockIdx.z;
    const int virt = (f & 7) * 32 + (f >> 3);
    const int bx   = virt & 7;
    const int by   = (virt >> 3) & 15;
    const int z    = virt >> 7;

    const int wr  = (wave >> 2) * 64;
    const int wc  = (wave & 3) * 64;
    const int bm0 = by * 128;
    const int bn0 = bx * 256;
    const int kb  = z * 1024;

    const int fr = lane & 15;
    const int gi = lane >> 4;

    // ---- staging geometry: 6 x 16B granules / thread / K-tile ----
    const int gr = tid >> 2;
    const int sw = 8 * ((tid & 3) ^ ((gr >> 1) & 3));

    const u16* sAh  = Qh + (size_t)(bm0 + gr) * KTOT + kb + sw;
    const u16* sAl  = Ql + (size_t)(bm0 + gr) * KTOT + kb + sw;
    const u16* sBh0 = Wh + (size_t)(bn0 + gr) * KTOT + kb + sw;
    const u16* sBh1 = Wh + (size_t)(bn0 + 128 + gr) * KTOT + kb + sw;
    const u16* sBl0 = Wl + (size_t)(bn0 + gr) * KTOT + kb + sw;
    const u16* sBl1 = Wl + (size_t)(bn0 + 128 + gr) * KTOT + kb + sw;

    uint32_t rOffB = 0;          // read buf byte offset
    uint32_t nOffB = 49152;      // next read buf byte offset
    uint32_t sOffU = 49152;      // stage buf u16 offset ((t+2)%3 * 24576)
    int      ktn   = 2;          // tile index being staged

    #define STAGE_A()  do { u16* Lb_ = ((u16*)L) + sOffU; const int ko = ktn * 32; \
        gload16(sAh  + ko, Lb_ + tid * 8);                                   \
        gload16(sAl  + ko, Lb_ + 4096  + tid * 8); } while (0)
    #define STAGE_BH() do { u16* Lb_ = ((u16*)L) + sOffU; const int ko = ktn * 32; \
        gload16(sBh0 + ko, Lb_ + 8192  + tid * 8);                           \
        gload16(sBh1 + ko, Lb_ + 12288 + tid * 8); } while (0)
    #define STAGE_BL() do { u16* Lb_ = ((u16*)L) + sOffU; const int ko = ktn * 32; \
        gload16(sBl0 + ko, Lb_ + 16384 + tid * 8);                           \
        gload16(sBl1 + ko, Lb_ + 20480 + tid * 8); } while (0)

    const uint32_t ldsBase = (uint32_t)(uintptr_t)&L[0][0];
    const uint32_t swz16   = (uint32_t)((gi ^ ((fr >> 1) & 3)) * 16);
    const uint32_t vbaseA  = ldsBase + (uint32_t)((wr + fr) * 64) + swz16;
    const uint32_t vbaseB  = ldsBase + 16384u + (uint32_t)((wc + fr) * 64) + swz16;

    #define RD_AB(OFFB) do { const uint32_t aA = vbaseA + (OFFB), aB = vbaseB + (OFFB); \
        RD16(ah[0], aA, "0");    RD16(ah[1], aA, "1024");                    \
        RD16(ah[2], aA, "2048"); RD16(ah[3], aA, "3072");                    \
        RD16(bh[0], aB, "0");    RD16(bh[1], aB, "1024");                    \
        RD16(bh[2], aB, "2048"); RD16(bh[3], aB, "3072"); } while (0)
    #define RD_AL() do { const uint32_t aA = vbaseA + rOffB;                 \
        RD16(al[0], aA, "8192");  RD16(al[1], aA, "9216");                   \
        RD16(al[2], aA, "10240"); RD16(al[3], aA, "11264"); } while (0)
    #define RD_BL() do { const uint32_t aB = vbaseB + rOffB;                 \
        RD16(bl[0], aB, "16384"); RD16(bl[1], aB, "17408");                  \
        RD16(bl[2], aB, "18432"); RD16(bl[3], aB, "19456"); } while (0)

    #define MF(AR, BR, M, N) \
        acc[M][N] = __builtin_amdgcn_mfma_f32_16x16x32_bf16(AR[M], BR[N], acc[M][N], 0, 0, 0)
    #define PASS(AR, BR) do {                                                \
        MF(AR, BR, 0, 0); MF(AR, BR, 0, 1); MF(AR, BR, 0, 2); MF(AR, BR, 0, 3); \
        MF(AR, BR, 1, 0); MF(AR, BR, 1, 1); MF(AR, BR, 1, 2); MF(AR, BR, 1, 3); \
        MF(AR, BR, 2, 0); MF(AR, BR, 2, 1); MF(AR, BR, 2, 2); MF(AR, BR, 2, 3); \
        MF(AR, BR, 3, 0); MF(AR, BR, 3, 1); MF(AR, BR, 3, 2); MF(AR, BR, 3, 3); \
    } while (0)

    // 3-phase K-tile. Reads for each pass were issued one phase earlier
    // (pre-barrier); lgkm(0) after each barrier waits only this wave's reads.
    #define TILE(DOSTAGE, DONEXT, VMS) do {                                  \
        /* ---- P1: pass hh ---- */                                         \
        if (doSnw) { GLD_F32(sn0, snwP);       GLD_F32(sn1, snwP + 128);     \
                     GLD_F32(sn2, snwP + 256); GLD_F32(sn3, snwP + 384); }   \
        if (DOSTAGE) STAGE_A();                                              \
        asm volatile("s_waitcnt lgkmcnt(0)");                                \
        __builtin_amdgcn_sched_barrier(0);                                   \
        __builtin_amdgcn_s_setprio(1);                                       \
        PASS(ah, bh);                                                        \
        __builtin_amdgcn_s_setprio(0);                                       \
        RD_AL();                                                             \
        __builtin_amdgcn_sched_barrier(0);                                   \
        __builtin_amdgcn_s_barrier();                                        \
        /* ---- P2: pass lh ---- */                                         \
        if (DOSTAGE) STAGE_BH();                                             \
        asm volatile("s_waitcnt lgkmcnt(0)");                                \
        __builtin_amdgcn_sched_barrier(0);                                   \
        __builtin_amdgcn_s_setprio(1);                                       \
        PASS(al, bh);                                                        \
        __builtin_amdgcn_s_setprio(0);                                       \
        RD_BL();                                                             \
        __builtin_amdgcn_sched_barrier(0);                                   \
        __builtin_amdgcn_s_barrier();                                        \
        /* ---- P3: pass hl + tile boundary ---- */                         \
        if (DOSTAGE) STAGE_BL();                                             \
        asm volatile("s_waitcnt lgkmcnt(0)");                                \
        __builtin_amdgcn_sched_barrier(0);                                   \
        __builtin_amdgcn_s_setprio(1);                                       \
        PASS(ah, bl);                                                        \
        __builtin_amdgcn_s_setprio(0);                                       \
        asm volatile("s_waitcnt vmcnt(" VMS ")");                            \
        if (DONEXT) RD_AB(nOffB);                                            \
        __builtin_amdgcn_sched_barrier(0);                                   \
        __builtin_amdgcn_s_barrier();                                        \
        rOffB = nOffB;                                                       \
        nOffB += 49152u; if (nOffB == 147456u) nOffB = 0;                    \
        sOffU += 24576u; if (sOffU == 73728u)  sOffU = 0;                    \
        ++ktn;                                                               \
    } while (0)

    bf16x8 ah[4], al[4], bh[4], bl[4];
    f32x4 acc[4][4], prod[4][4];
    float sn0, sn1, sn2, sn3;
    #pragma unroll
    for (int m = 0; m < 4; ++m)
        #pragma unroll
        for (int n = 0; n < 4; ++n) {
            acc[m][n]  = (f32x4){0.f, 0.f, 0.f, 0.f};
            prod[m][n] = (f32x4){1.f, 1.f, 1.f, 1.f};
        }

    const float* snwBase = snw + (size_t)(bn0 + wc + fr) * NV + z * 4;

    // prologue: stage tiles 0 (buf0) and 1 (buf1); wait tile 0 only;
    // preload ah/bh of tile 0 from buf0.
    sOffU = 0;     ktn = 0; STAGE_A(); STAGE_BH(); STAGE_BL();
    sOffU = 24576; ktn = 1; STAGE_A(); STAGE_BH(); STAGE_BL();
    sOffU = 49152; ktn = 2;
    asm volatile("s_waitcnt vmcnt(6)");
    __builtin_amdgcn_s_barrier();
    RD_AB(0u);

    #pragma unroll 1
    for (int t = 0; t < 30; ++t) {
        const bool doSnw = ((t & 7) == 7);
        const float* snwP = snwBase + (t >> 3);
        TILE(1, 1, "6");
        if (doSnw) chunk_epi(acc, prod, sn0, sn1, sn2, sn3);
    }
    {   // t = 30: no stage left; drain stage(31) before next-tile reads
        const bool doSnw = false;
        const float* snwP = snwBase;
        TILE(0, 1, "0");
    }
    {   // t = 31: last tile; snw for chunk 3; drain snw before epilogue
        const bool doSnw = true;
        const float* snwP = snwBase + 3;
        TILE(0, 0, "0");
        chunk_epi(acc, prod, sn0, sn1, sn2, sn3);
    }

    const int ri = gi * 4;
    float* P = part + (size_t)z * BATCH * NCHOICES;
    #pragma unroll
    for (int m = 0; m < 4; ++m)
        #pragma unroll
        for (int i = 0; i < 4; ++i) {
            const int row = bm0 + wr + m * 16 + ri + i;
            float* pr = P + (size_t)row * NCHOICES + bn0 + wc + fr;
            #pragma unroll
            for (int n = 0; n < 4; ++n) pr[n * 16] = prod[m][n][i];
        }

    #undef STAGE_A
    #undef STAGE_BH
    #undef STAGE_BL
    #undef RD_AB
    #undef RD_AL
    #undef RD_BL
    #undef MF
    #undef PASS
    #undef TILE
}

// ---------------------------------------------------------------------------
// Kernel 3: combine 2 split-K partial products.
// ---------------------------------------------------------------------------
__global__ __launch_bounds__(256) void combine_kernel(
    const float* __restrict__ p, float* __restrict__ out)
{
    const size_t NN = (size_t)BATCH * NCHOICES;
    size_t i = ((size_t)blockIdx.x * 256 + threadIdx.x) * 4;
    float4 a = *(const float4*)(p + i);
    float4 b = *(const float4*)(p + NN + i);
    float4 o;
    o.x = a.x * b.x;
    o.y = a.y * b.y;
    o.z = a.z * b.z;
    o.w = a.w * b.w;
    *(float4*)(out + i) = o;
}

// ---------------------------------------------------------------------------
// Fallback: R1's verified fp32 vector-FMA path (used if ws too small).
// ---------------------------------------------------------------------------
__global__ __launch_bounds__(256) void prep_kernel(
    const float* __restrict__ Q, const float* __restrict__ W,
    const float* __restrict__ NWT,
    float* __restrict__ rq, float* __restrict__ rw, float* __restrict__ snw)
{
    const int row = blockIdx.x;
    const int t   = threadIdx.x;
    const int n   = t >> 5;
    const int l   = t & 31;

    const float* src; float* dst;
    if (row < BATCH) { src = Q + (size_t)row * KTOT; dst = rq + (size_t)row * NV; }
    else { src = W + (size_t)(row - BATCH) * KTOT; dst = rw + (size_t)(row - BATCH) * NV; }

    const float* v = src + n * VS + l * 8;
    float4 a = *(const float4*)(v);
    float4 b = *(const float4*)(v + 4);
    float s = a.x*a.x + a.y*a.y + a.z*a.z + a.w*a.w
            + b.x*b.x + b.y*b.y + b.z*b.z + b.w*b.w;
    #pragma unroll
    for (int m = 1; m < 32; m <<= 1) s += __shfl_xor(s, m, 64);
    if (l == 0) dst[n] = 1.0f / fmaxf(sqrtf(s), 1e-6f);
    if (row >= BATCH && t < NV) {
        const int c = row - BATCH;
        float x = NWT[(size_t)c * NV + t];
        snw[(size_t)c * NV + t] = 1.0f / (1.0f + expf(-x));
    }
}

__global__ __launch_bounds__(256, 2) void nand_gemm(
    const float* __restrict__ Q, const float* __restrict__ W,
    const float* __restrict__ rq, const float* __restrict__ rw,
    const float* __restrict__ snw, float* __restrict__ out)
{
    __shared__ __align__(16) float As[16][128 + 4];
    __shared__ __align__(16) float Bs[16][128 + 4];
    __shared__ __align__(16) float rqs[128];
    __shared__ __align__(16) float rws[128];
    __shared__ __align__(16) float sns[128];

    const int tid = threadIdx.x;
    const int tx  = tid & 15;
    const int ty  = tid >> 4;
    const int bm0 = blockIdx.y * 128;
    const int bn0 = blockIdx.x * 128;
    const int lr  = tid >> 2;
    const int lk  = (tid & 3) * 4;

    float prod[8][8];
    #pragma unroll
    for (int i = 0; i < 8; ++i)
        #pragma unroll
        for (int j = 0; j < 8; ++j) prod[i][j] = 1.0f;

    for (int n = 0; n < NV; ++n) {
        float acc[8][8];
        #pragma unroll
        for (int i = 0; i < 8; ++i)
            #pragma unroll
            for (int j = 0; j < 8; ++j) acc[i][j] = 0.0f;

        #pragma unroll 1
        for (int kt = 0; kt < VS / 16; ++kt) {
            const int k0 = n * VS + kt * 16;
            __syncthreads();
            {
                const float* qrow = Q + (size_t)(bm0 + lr) * KTOT + k0 + lk;
                float4 a0 = *(const float4*)(qrow);
                float4 a1 = *(const float4*)(qrow + (size_t)64 * KTOT);
                As[lk + 0][lr] = a0.x; As[lk + 1][lr] = a0.y;
                As[lk + 2][lr] = a0.z; As[lk + 3][lr] = a0.w;
                As[lk + 0][64 + lr] = a1.x; As[lk + 1][64 + lr] = a1.y;
                As[lk + 2][64 + lr] = a1.z; As[lk + 3][64 + lr] = a1.w;

                const float* wrow = W + (size_t)(bn0 + lr) * KTOT + k0 + lk;
                float4 b0 = *(const float4*)(wrow);
                float4 b1 = *(const float4*)(wrow + (size_t)64 * KTOT);
                Bs[lk + 0][lr] = b0.x; Bs[lk + 1][lr] = b0.y;
                Bs[lk + 2][lr] = b0.z; Bs[lk + 3][lr] = b0.w;
                Bs[lk + 0][64 + lr] = b1.x; Bs[lk + 1][64 + lr] = b1.y;
                Bs[lk + 2][64 + lr] = b1.z; Bs[lk + 3][64 + lr] = b1.w;
            }
            if (kt == 0) {
                for (int i = tid; i < 3 * 128; i += 256) {
                    if (i < 128)      rqs[i]       = rq[(size_t)(bm0 + i) * NV + n];
                    else if (i < 256) rws[i - 128] = rw[(size_t)(bn0 + i - 128) * NV + n];
                    else              sns[i - 256] = snw[(size_t)(bn0 + i - 256) * NV + n];
                }
            }
            __syncthreads();

            #pragma unroll
            for (int kk = 0; kk < 16; ++kk) {
                float4 a0 = *(const float4*)&As[kk][ty * 4];
                float4 a1 = *(const float4*)&As[kk][64 + ty * 4];
                float4 b0 = *(const float4*)&Bs[kk][tx * 4];
                float4 b1 = *(const float4*)&Bs[kk][64 + tx * 4];
                float ar[8] = {a0.x, a0.y, a0.z, a0.w, a1.x, a1.y, a1.z, a1.w};
                float br[8] = {b0.x, b0.y, b0.z, b0.w, b1.x, b1.y, b1.z, b1.w};
                #pragma unroll
                for (int i = 0; i < 8; ++i)
                    #pragma unroll
                    for (int j = 0; j < 8; ++j)
                        acc[i][j] = fmaf(ar[i], br[j], acc[i][j]);
            }
        }

        float rwv[8], uu[8], vv[8];
        #pragma unroll
        for (int j = 0; j < 8; ++j) {
            int cc = (j < 4) ? (tx * 4 + j) : (64 + tx * 4 + (j - 4));
            rwv[j] = rws[cc];
            float s = sns[cc];
            uu[j] = 1.0f - s;
            vv[j] = 2.0f * s - 1.0f;
        }
        #pragma unroll
        for (int i = 0; i < 8; ++i) {
            int r = (i < 4) ? (ty * 4 + i) : (64 + ty * 4 + (i - 4));
            float rqv = rqs[r];
            #pragma unroll
            for (int j = 0; j < 8; ++j) {
                float cosv = acc[i][j] * rqv * rwv[j];
                float Lk = fmaxf(cosv, 0.01f * cosv);
                prod[i][j] *= fmaf(Lk, vv[j], uu[j]);
            }
        }
    }

    #pragma unroll
    for (int i = 0; i < 8; ++i) {
        int r = (i < 4) ? (ty * 4 + i) : (64 + ty * 4 + (i - 4));
        float* orow = out + (size_t)(bm0 + r) * NCHOICES + bn0;
        float4 o0 = {prod[i][0], prod[i][1], prod[i][2], prod[i][3]};
        float4 o1 = {prod[i][4], prod[i][5], prod[i][6], prod[i][7]};
        *(float4*)(orow + tx * 4)      = o0;
        *(float4*)(orow + 64 + tx * 4) = o1;
    }
}

extern "C" void kernel_launch(void* const* d_in, const int* in_sizes, int n_in,
                              void* d_out, int out_size, void* d_ws, size_t ws_size,
                              hipStream_t stream)
{
    const float* Q   = (const float*)d_in[0];
    const float* W   = (const float*)d_in[1];
    const float* NWT = (const float*)d_in[2];
    float* out = (float*)d_out;

    char* w = (char*)d_ws;
    float* rq  = (float*)w; w += (size_t)BATCH    * NV * 4;
    float* rwn = (float*)w; w += (size_t)NCHOICES * NV * 4;
    float* snw = (float*)w; w += (size_t)NCHOICES * NV * 4;
    u16* Qh = (u16*)w; w += (size_t)BATCH * KTOT * 2;
    u16* Ql = (u16*)w; w += (size_t)BATCH * KTOT * 2;
    u16* Wh = (u16*)w; w += (size_t)NCHOICES * KTOT * 2;
    u16* Wl = (u16*)w; w += (size_t)NCHOICES * KTOT * 2;
    float* part = (float*)w; w += (size_t)2 * BATCH * NCHOICES * 4;
    const size_t needed = (size_t)(w - (char*)d_ws);

    if (ws_size >= needed) {
        prep_convert<<<BATCH + NCHOICES, 256, 0, stream>>>(
            Q, W, NWT, Qh, Ql, Wh, Wl, snw);
        dim3 grid(NCHOICES / 256, BATCH / 128, 2);
        nand_mfma12<<<grid, 512, 0, stream>>>(Qh, Ql, Wh, Wl, snw, part);
        combine_kernel<<<(BATCH * NCHOICES / 4) / 256, 256, 0, stream>>>(part, out);
    } else {
        prep_kernel<<<BATCH + NCHOICES, 256, 0, stream>>>(Q, W, NWT, rq, rwn, snw);
        dim3 grid(NCHOICES / 128, BATCH / 128);
        nand_gemm<<<grid, 256, 0, stream>>>(Q, W, rq, rwn, snw, out);
    }
}